// Round 1
// baseline (3787.081 us; speedup 1.0000x reference)
//
#include <hip/hip_runtime.h>
#include <cstddef>
#include <cstdint>

// Problem constants (B=2, S=2048, E=1024, H=16, D=64)
#define BATCH 2
#define S_LEN 2048
#define E_DIM 1024
#define NH    16
#define HD    64
#define M_ROWS (BATCH * S_LEN)   // 4096

// ---------------------------------------------------------------------------
// GEMM (NT): C[m,n] = sum_k A[m,k] * B[n,k] + bias[n]
// A: [M,K] row-major, B: [N,K] row-major (i.e. torch Linear weight), C: [M,N]
// 128x128 tile, BK=8, 256 threads, 8x8 accumulators per thread.
// ---------------------------------------------------------------------------
#define GBM 128
#define GBN 128
#define GBK 8

__global__ __launch_bounds__(256)
void gemm_nt(const float* __restrict__ A, const float* __restrict__ B,
             const float* __restrict__ bias, float* __restrict__ C,
             int M, int N, int K)
{
    __shared__ float As[GBK][GBM + 4];
    __shared__ float Bs[GBK][GBN + 4];
    const int tid = threadIdx.x;
    const int tx  = tid & 15;          // n within tile
    const int ty  = tid >> 4;          // m within tile
    const int m0  = blockIdx.x * GBM;
    const int n0  = blockIdx.y * GBN;
    const int lrow = tid >> 1;         // 0..127 (load row)
    const int lcol = (tid & 1) * 4;    // 0 or 4 (load col)

    float acc[8][8];
#pragma unroll
    for (int i = 0; i < 8; ++i)
#pragma unroll
        for (int j = 0; j < 8; ++j) acc[i][j] = 0.f;

    for (int kb = 0; kb < K; kb += GBK) {
        const float4 a4 = *(const float4*)(A + (size_t)(m0 + lrow) * K + kb + lcol);
        const float4 b4 = *(const float4*)(B + (size_t)(n0 + lrow) * K + kb + lcol);
        __syncthreads();   // protect previous iteration's LDS reads
        As[lcol + 0][lrow] = a4.x; As[lcol + 1][lrow] = a4.y;
        As[lcol + 2][lrow] = a4.z; As[lcol + 3][lrow] = a4.w;
        Bs[lcol + 0][lrow] = b4.x; Bs[lcol + 1][lrow] = b4.y;
        Bs[lcol + 2][lrow] = b4.z; Bs[lcol + 3][lrow] = b4.w;
        __syncthreads();
#pragma unroll
        for (int kk = 0; kk < GBK; ++kk) {
            float a[8], b[8];
#pragma unroll
            for (int i = 0; i < 8; ++i) a[i] = As[kk][ty + 16 * i];
#pragma unroll
            for (int j = 0; j < 8; ++j) b[j] = Bs[kk][tx + 16 * j];
#pragma unroll
            for (int i = 0; i < 8; ++i)
#pragma unroll
                for (int j = 0; j < 8; ++j) acc[i][j] += a[i] * b[j];
        }
    }

#pragma unroll
    for (int i = 0; i < 8; ++i) {
        const size_t m = (size_t)(m0 + ty + 16 * i);
#pragma unroll
        for (int j = 0; j < 8; ++j) {
            const int n = n0 + tx + 16 * j;
            C[m * N + n] = acc[i][j] + bias[n];
        }
    }
}

// ---------------------------------------------------------------------------
// Fused attention with softmax over the HEADS axis (the reference quirk).
// scores[b,h,q,k] = dot64(Q[b,q,h,:], K[b,k,h,:]) / 8
// attn = softmax over h (local per (b,q,k) -> 16 values in registers!)
// ctx[b,q,h*64+d] = sum_k attn[b,h,q,k] * V[b,k,h,d]
//
// Grid: BATCH * (S/TQ) = 256 blocks, 256 threads.
// Thread (qi = tid>>4, lo = tid&15):
//   phase 1: owns the (qi, kj=lo) score pair, 16 head accumulators in regs
//   phase 3: owns output O[h][q0+qi][d = lo*4 .. lo*4+3] for all 16 heads
// LDS: Qc[16][260] / Kc[16][260] fp32 chunks (stride 260 -> <=2-way bank
// conflict which is free), wsm[16][16][16] weights; Vs aliases Qc.
// Total ~49.7 KB static LDS.
// ---------------------------------------------------------------------------
#define TQ  16
#define TK  16
#define CST 260   // chunk row stride in floats (256 data + 4 pad, keeps 16B align)

__global__ __launch_bounds__(256)
void attn_fused(const float* __restrict__ q, const float* __restrict__ k,
                const float* __restrict__ v, float* __restrict__ ctx)
{
    __shared__ float smem[2 * 16 * CST + NH * TQ * TK];
    float* Qc  = smem;                   // [16][CST]  (phase 1)
    float* Kc  = smem + 16 * CST;        // [16][CST]  (phase 1)
    float* wsm = smem + 2 * 16 * CST;    // [h][qi][kj]
    float* Vs  = smem;                   // [16][CST]  (phase 3, aliases Qc)

    const int tid = threadIdx.x;
    const int b   = blockIdx.x >> 7;     // 128 q-tiles per batch
    const int qt  = blockIdx.x & 127;
    const int q0  = qt * TQ;
    const int qi  = tid >> 4;            // 0..15
    const int lo  = tid & 15;            // kj (phase 1) / d-lane (phase 3)

    const size_t qbase = ((size_t)b * S_LEN + q0) * E_DIM;

    float o[NH][4];
#pragma unroll
    for (int h = 0; h < NH; ++h)
#pragma unroll
        for (int j = 0; j < 4; ++j) o[h][j] = 0.f;

    // staging map: flat = u*1024 + tid*4 over a 16x256 chunk
    const int sr  = tid >> 6;            // row = u*4 + sr
    const int scg = (tid & 63) * 4;      // col (multiple of 4)

    for (int kt = 0; kt < S_LEN / TK; ++kt) {
        const int k0 = kt * TK;
        const size_t kbase = ((size_t)b * S_LEN + k0) * E_DIM;

        // ---- phase 1: scores for all 16 heads of this (qi,kj) pair ----
        float sc[NH];
#pragma unroll
        for (int h = 0; h < NH; ++h) sc[h] = 0.f;

        for (int ec = 0; ec < 4; ++ec) {       // 256-wide e-chunks (4 heads each)
            __syncthreads();                   // previous-phase LDS reads done
#pragma unroll
            for (int u = 0; u < 4; ++u) {
                const int r = u * 4 + sr;
                const float4 qv = *(const float4*)(q + qbase + (size_t)r * E_DIM + ec * 256 + scg);
                const float4 kv = *(const float4*)(k + kbase + (size_t)r * E_DIM + ec * 256 + scg);
                *(float4*)&Qc[r * CST + scg] = qv;
                *(float4*)&Kc[r * CST + scg] = kv;
            }
            __syncthreads();
#pragma unroll
            for (int h2 = 0; h2 < 4; ++h2) {
                float s0 = 0.f, s1 = 0.f, s2 = 0.f, s3 = 0.f;
#pragma unroll
                for (int d4 = 0; d4 < 16; ++d4) {
                    const float4 qv = *(const float4*)&Qc[qi * CST + h2 * 64 + d4 * 4];
                    const float4 kv = *(const float4*)&Kc[lo * CST + h2 * 64 + d4 * 4];
                    s0 += qv.x * kv.x; s1 += qv.y * kv.y;
                    s2 += qv.z * kv.z; s3 += qv.w * kv.w;
                }
                sc[ec * 4 + h2] = (s0 + s1) + (s2 + s3);
            }
        }

        // ---- phase 2: softmax over heads, entirely in registers ----
        float mx = sc[0];
#pragma unroll
        for (int h = 1; h < NH; ++h) mx = fmaxf(mx, sc[h]);
        float w[NH];
        float sum = 0.f;
#pragma unroll
        for (int h = 0; h < NH; ++h) {
            w[h] = __expf((sc[h] - mx) * 0.125f);   // scale 1/sqrt(64)=1/8
            sum += w[h];
        }
        const float inv = 1.f / sum;
#pragma unroll
        for (int h = 0; h < NH; ++h)
            wsm[h * (TQ * TK) + qi * TK + lo] = w[h] * inv;

        // ---- phase 3: O[h][qi][d] += w[h][qi][kj] * V[kj][h][d] ----
        for (int hg = 0; hg < 4; ++hg) {       // head groups of 4
            __syncthreads();                   // Qc reads done; wsm visible after next barrier
#pragma unroll
            for (int u = 0; u < 4; ++u) {
                const int r = u * 4 + sr;
                const float4 vv = *(const float4*)(v + kbase + (size_t)r * E_DIM + hg * 256 + scg);
                *(float4*)&Vs[r * CST + scg] = vv;
            }
            __syncthreads();
#pragma unroll
            for (int h2 = 0; h2 < 4; ++h2) {
                const int h = hg * 4 + h2;
                float wr[16];
#pragma unroll
                for (int g = 0; g < 4; ++g) {
                    const float4 w4 = *(const float4*)&wsm[h * (TQ * TK) + qi * TK + 4 * g];
                    wr[4 * g + 0] = w4.x; wr[4 * g + 1] = w4.y;
                    wr[4 * g + 2] = w4.z; wr[4 * g + 3] = w4.w;
                }
                float a0 = o[h][0], a1 = o[h][1], a2 = o[h][2], a3 = o[h][3];
#pragma unroll
                for (int kj = 0; kj < 16; ++kj) {
                    const float4 vv = *(const float4*)&Vs[kj * CST + h2 * 64 + lo * 4];
                    a0 += wr[kj] * vv.x; a1 += wr[kj] * vv.y;
                    a2 += wr[kj] * vv.z; a3 += wr[kj] * vv.w;
                }
                o[h][0] = a0; o[h][1] = a1; o[h][2] = a2; o[h][3] = a3;
            }
        }
    }

    // ---- write ctx[b, q0+qi, h*64 + lo*4 .. +3] (transposed to [B,S,E]) ----
    const size_t obase = ((size_t)b * S_LEN + q0 + qi) * E_DIM;
#pragma unroll
    for (int h = 0; h < NH; ++h) {
        float4 st;
        st.x = o[h][0]; st.y = o[h][1]; st.z = o[h][2]; st.w = o[h][3];
        *(float4*)&ctx[obase + h * 64 + lo * 4] = st;
    }
}

// ---------------------------------------------------------------------------
extern "C" void kernel_launch(void* const* d_in, const int* in_sizes, int n_in,
                              void* d_out, int out_size, void* d_ws, size_t ws_size,
                              hipStream_t stream)
{
    const float* x  = (const float*)d_in[0];
    const float* Wq = (const float*)d_in[1];
    const float* bq = (const float*)d_in[2];
    const float* Wk = (const float*)d_in[3];
    const float* bk = (const float*)d_in[4];
    const float* Wv = (const float*)d_in[5];
    const float* bv = (const float*)d_in[6];
    const float* Wo = (const float*)d_in[7];
    const float* bo = (const float*)d_in[8];
    float* out = (float*)d_out;

    // workspace layout (fp32): q | k | v | ctx  (16 MB each, 64 MB total)
    const size_t MAT = (size_t)M_ROWS * E_DIM;
    float* qb  = (float*)d_ws;
    float* kb2 = qb + MAT;
    float* vb  = kb2 + MAT;
    float* cb  = vb + MAT;

    dim3 ggrid(M_ROWS / GBM, E_DIM / GBN);   // 32 x 8 = 256 blocks
    gemm_nt<<<ggrid, 256, 0, stream>>>(x, Wq, bq, qb,  M_ROWS, E_DIM, E_DIM);
    gemm_nt<<<ggrid, 256, 0, stream>>>(x, Wk, bk, kb2, M_ROWS, E_DIM, E_DIM);
    gemm_nt<<<ggrid, 256, 0, stream>>>(x, Wv, bv, vb,  M_ROWS, E_DIM, E_DIM);

    attn_fused<<<BATCH * (S_LEN / TQ), 256, 0, stream>>>(qb, kb2, vb, cb);

    gemm_nt<<<ggrid, 256, 0, stream>>>(cb, Wo, bo, out, M_ROWS, E_DIM, E_DIM);
}